// Round 9
// baseline (377.528 us; speedup 1.0000x reference)
//
#include <hip/hip_runtime.h>
#include <hip/hip_bf16.h>

#define N_NODES 100000
#define N_EDGES 1600000
#define IN_FEA 128
#define HIDDEN 128
#define RANK 64

#define NBUCK 391          // ceil(N_NODES/256): bucket b = nodes [b*256, b*256+256)
#define C_BLOCKS 1024      // hist blocks
#define EPB 1563           // edges per hist block
#define CHUNKS 128         // binscatter chunks
#define CHUNK_W (EPB * 8)  // 12504 edges per chunk (= 8 hist blocks)
#define GEMM1_BLOCKS 1563  // ceil(N_NODES / 64)
#define AGG_BLOCKS 512

// ---------------- helpers ----------------

__device__ __forceinline__ void fma4(float4& a, float s, const float4& b) {
    a.x = fmaf(s, b.x, a.x);
    a.y = fmaf(s, b.y, a.y);
    a.z = fmaf(s, b.z, a.z);
    a.w = fmaf(s, b.w, a.w);
}

__device__ __forceinline__ unsigned short f2bf_rne(float f) {
    unsigned u = __float_as_uint(f);
    u += 0x7fffu + ((u >> 16) & 1u);
    return (unsigned short)(u >> 16);
}

__device__ __forceinline__ float bf2f(unsigned short s) {
    return __uint_as_float(((unsigned)s) << 16);
}

// ---------------- fused GEMM1 + bucket histogram ----------------
// blocks [0, GEMM1_BLOCKS): h_bf = bf16(x @ W), 64 nodes/block.
// blocks [GEMM1_BLOCKS, +C_BLOCKS): per-block bucket histogram (EPB edges each).

__global__ __launch_bounds__(256) void gemm1_hist_kernel(const float* __restrict__ x,
                                                         const float* __restrict__ W,
                                                         unsigned short* __restrict__ hb,
                                                         const int* __restrict__ dst,
                                                         int* __restrict__ bhist,
                                                         int* __restrict__ blockhist) {
    __shared__ float Wl[IN_FEA * RANK];  // 32 KB (hist aliases first 1.6 KB)
    int t = threadIdx.x;

    if (blockIdx.x >= GEMM1_BLOCKS) {
        int* hist = (int*)Wl;
        int b = blockIdx.x - GEMM1_BLOCKS;
        for (int i = t; i < NBUCK; i += 256) hist[i] = 0;
        __syncthreads();
        int b0 = b * EPB;
        int b1 = min(b0 + EPB, N_EDGES);
        for (int e = b0 + t; e < b1; e += 256)
            atomicAdd(&hist[dst[e] >> 8], 1);
        __syncthreads();
        for (int i = t; i < NBUCK; i += 256) {
            int c = hist[i];
            blockhist[b * NBUCK + i] = c;
            if (c) atomicAdd(&bhist[i], c);
        }
        return;
    }

    for (int i = t; i < IN_FEA * RANK; i += 256) Wl[i] = W[i];
    __syncthreads();

    int r0 = (t & 15) * 4;
    int n0 = blockIdx.x * 64 + (t >> 4) * 4;
    const float4* x0 = (const float4*)(x + (long)min(n0 + 0, N_NODES - 1) * IN_FEA);
    const float4* x1 = (const float4*)(x + (long)min(n0 + 1, N_NODES - 1) * IN_FEA);
    const float4* x2 = (const float4*)(x + (long)min(n0 + 2, N_NODES - 1) * IN_FEA);
    const float4* x3 = (const float4*)(x + (long)min(n0 + 3, N_NODES - 1) * IN_FEA);
    float4 a0 = {0.f, 0.f, 0.f, 0.f}, a1 = a0, a2 = a0, a3 = a0;
    for (int k4 = 0; k4 < IN_FEA / 4; ++k4) {
        float4 v0 = x0[k4], v1 = x1[k4], v2 = x2[k4], v3 = x3[k4];
        int kb = k4 * 4;
        float4 w0 = *(const float4*)&Wl[(kb + 0) * RANK + r0];
        float4 w1 = *(const float4*)&Wl[(kb + 1) * RANK + r0];
        float4 w2 = *(const float4*)&Wl[(kb + 2) * RANK + r0];
        float4 w3 = *(const float4*)&Wl[(kb + 3) * RANK + r0];
        fma4(a0, v0.x, w0); fma4(a0, v0.y, w1); fma4(a0, v0.z, w2); fma4(a0, v0.w, w3);
        fma4(a1, v1.x, w0); fma4(a1, v1.y, w1); fma4(a1, v1.z, w2); fma4(a1, v1.w, w3);
        fma4(a2, v2.x, w0); fma4(a2, v2.y, w1); fma4(a2, v2.z, w2); fma4(a2, v2.w, w3);
        fma4(a3, v3.x, w0); fma4(a3, v3.y, w1); fma4(a3, v3.z, w2); fma4(a3, v3.w, w3);
    }
    float4 accs[4] = {a0, a1, a2, a3};
#pragma unroll
    for (int i = 0; i < 4; ++i) {
        if (n0 + i < N_NODES) {
            ushort4 o;
            o.x = f2bf_rne(accs[i].x); o.y = f2bf_rne(accs[i].y);
            o.z = f2bf_rne(accs[i].z); o.w = f2bf_rne(accs[i].w);
            *(ushort4*)(hb + (n0 + i) * RANK + r0) = o;
        }
    }
}

// ---------------- CSR build (rest) ----------------

__global__ void bucket_scan_kernel(const int* __restrict__ bhist,
                                   int* __restrict__ bucket_offs,
                                   int* __restrict__ bucket_cursor,
                                   int* __restrict__ offs) {
    __shared__ int sd[512];
    int t = threadIdx.x;
    int v = (t < NBUCK) ? bhist[t] : 0;
    sd[t] = v;
    __syncthreads();
    for (int off = 1; off < 512; off <<= 1) {
        int a = 0;
        if (t >= off) a = sd[t - off];
        __syncthreads();
        sd[t] += a;
        __syncthreads();
    }
    if (t < NBUCK) {
        int excl = sd[t] - v;
        bucket_offs[t] = excl;
        bucket_cursor[t] = excl;
    }
    if (t == 0) {
        bucket_offs[NBUCK] = N_EDGES;
        offs[N_NODES] = N_EDGES;
    }
}

// XCD-partitioned scatter: block i -> XCD x=i%8 handles only buckets b%8==x over
// chunk i>>3. All writers of a bucket's pairs region run on one XCD -> dirty
// lines fill completely in that XCD's L2 (kills partial-line write amplification).
__global__ __launch_bounds__(256) void binscatter_kernel(const int* __restrict__ src,
                                                         const int* __restrict__ dst,
                                                         const int* __restrict__ blockhist,
                                                         int* __restrict__ bucket_cursor,
                                                         unsigned* __restrict__ pairs) {
    __shared__ int wbase[NBUCK];
    __shared__ int cur[NBUCK];
    int t = threadIdx.x;
    int x = blockIdx.x & 7;
    int c = blockIdx.x >> 3;
    // reserve ranges for this XCD's buckets; count = sum of the chunk's 8 hist rows
    if (t < 49) {
        int b = x + (t << 3);
        if (b < NBUCK) {
            int s = 0;
#pragma unroll
            for (int k = 0; k < 8; ++k)
                s += blockhist[(8 * c + k) * NBUCK + b];
            wbase[b] = s ? atomicAdd(&bucket_cursor[b], s) : 0;
            cur[b] = 0;
        }
    }
    __syncthreads();
    int e0 = c * CHUNK_W;
    int e1 = min(e0 + CHUNK_W, N_EDGES);
    for (int e = e0 + t; e < e1; e += 256) {
        int d = dst[e];
        int bk = d >> 8;
        if ((bk & 7) == x) {
            int s = src[e];
            int lp = atomicAdd(&cur[bk], 1);
            pairs[wbase[bk] + lp] = ((unsigned)s << 8) | (unsigned)(d & 255);
        }
    }
}

__global__ __launch_bounds__(256) void bucket_build_kernel(const unsigned* __restrict__ pairs,
                                                           const int* __restrict__ bucket_offs,
                                                           int* __restrict__ offs,
                                                           int* __restrict__ eidx) {
    __shared__ int dcnt[256];
    __shared__ int sd[256];
    __shared__ int cur[256];
    int b = blockIdx.x, t = threadIdx.x;
    int base = bucket_offs[b], end = bucket_offs[b + 1];
    dcnt[t] = 0;
    __syncthreads();
    for (int i = base + t; i < end; i += 256)
        atomicAdd(&dcnt[pairs[i] & 255u], 1);
    __syncthreads();
    int v = dcnt[t];
    sd[t] = v;
    __syncthreads();
    for (int off = 1; off < 256; off <<= 1) {
        int a = 0;
        if (t >= off) a = sd[t - off];
        __syncthreads();
        sd[t] += a;
        __syncthreads();
    }
    int excl = sd[t] - v;
    int node = b * 256 + t;
    if (node < N_NODES) offs[node] = base + excl;
    cur[t] = excl;
    __syncthreads();
    for (int i = base + t; i < end; i += 256) {
        unsigned r = pairs[i];
        int lp = atomicAdd(&cur[r & 255u], 1);
        eidx[base + lp] = (int)(r >> 8);
    }
}

// ---------------- fused aggregation + GEMM2 (persistent) ----------------
// 512 blocks x 1024 threads (2 blocks/CU, 32 waves/CU). V staged fp32 ONCE per
// block (VL[128][68], 16B-aligned rows); single barrier at start. Each wave
// loops over nodes (one node per wave-iteration -> 100k independent gather
// streams); pls slab is wave-private so no further syncs.

__global__ __launch_bounds__(1024) void agg_gemm_kernel(const unsigned short* __restrict__ hb,
                                                        const float* __restrict__ norm,
                                                        const float* __restrict__ V,
                                                        const int* __restrict__ offs,
                                                        const int* __restrict__ eidx,
                                                        float* __restrict__ out) {
    __shared__ float VL[HIDDEN * 68];   // 34,816 B
    __shared__ float pls[16][64];       // 4 KB
    int t = threadIdx.x;
    {
        const float4* V4 = (const float4*)V;
#pragma unroll
        for (int k = 0; k < 2; ++k) {
            int i4 = t + 1024 * k;
            float4 v = V4[i4];
            int el = i4 << 2;
            *(float4*)&VL[(el >> 6) * 68 + (el & 63)] = v;
        }
    }
    __syncthreads();

    int wave = t >> 6, lane = t & 63;
    int wid = blockIdx.x * 16 + wave;              // 0..8191
    const float4* pw = (const float4*)pls[wave];
    const float4* rA = (const float4*)&VL[lane * 68];
    const float4* rB = (const float4*)&VL[(lane + 64) * 68];

    for (int node = wid; node < N_NODES; node += AGG_BLOCKS * 16) {
        int beg = offs[node], end = offs[node + 1];
        float p = 1.0f;
        for (int c = beg; c < end; c += 64) {
            int n = min(64, end - c);
            int sidx = (c + lane < end) ? eidx[c + lane] : 0;
            int j = 0;
            for (; j + 8 <= n; j += 8) {
                int s0 = __shfl(sidx, j + 0);
                int s1 = __shfl(sidx, j + 1);
                int s2 = __shfl(sidx, j + 2);
                int s3 = __shfl(sidx, j + 3);
                int s4 = __shfl(sidx, j + 4);
                int s5 = __shfl(sidx, j + 5);
                int s6 = __shfl(sidx, j + 6);
                int s7 = __shfl(sidx, j + 7);
                float a0 = bf2f(hb[s0 * RANK + lane]);
                float a1 = bf2f(hb[s1 * RANK + lane]);
                float a2 = bf2f(hb[s2 * RANK + lane]);
                float a3 = bf2f(hb[s3 * RANK + lane]);
                float a4 = bf2f(hb[s4 * RANK + lane]);
                float a5 = bf2f(hb[s5 * RANK + lane]);
                float a6 = bf2f(hb[s6 * RANK + lane]);
                float a7 = bf2f(hb[s7 * RANK + lane]);
                p *= ((a0 * a1) * (a2 * a3)) * ((a4 * a5) * (a6 * a7));
            }
            for (; j + 4 <= n; j += 4) {
                int s0 = __shfl(sidx, j + 0);
                int s1 = __shfl(sidx, j + 1);
                int s2 = __shfl(sidx, j + 2);
                int s3 = __shfl(sidx, j + 3);
                float a0 = bf2f(hb[s0 * RANK + lane]);
                float a1 = bf2f(hb[s1 * RANK + lane]);
                float a2 = bf2f(hb[s2 * RANK + lane]);
                float a3 = bf2f(hb[s3 * RANK + lane]);
                p *= (a0 * a1) * (a2 * a3);
            }
            for (; j < n; ++j) {
                int s = __shfl(sidx, j);
                p *= bf2f(hb[s * RANK + lane]);
            }
        }
        pls[wave][lane] = p * norm[node];
        // wave-private slab: no barrier needed

        float accA = 0.f, accB = 0.f;
#pragma unroll
        for (int q = 0; q < 16; ++q) {
            float4 pp = pw[q];                  // broadcast read
            float4 va = rA[q];
            float4 vb = rB[q];
            accA = fmaf(pp.x, va.x, fmaf(pp.y, va.y, fmaf(pp.z, va.z, fmaf(pp.w, va.w, accA))));
            accB = fmaf(pp.x, vb.x, fmaf(pp.y, vb.y, fmaf(pp.z, vb.z, fmaf(pp.w, vb.w, accB))));
        }
        out[node * HIDDEN + lane]      = accA;
        out[node * HIDDEN + 64 + lane] = accB;
    }
}

// ---------------- launch ----------------

extern "C" void kernel_launch(void* const* d_in, const int* in_sizes, int n_in,
                              void* d_out, int out_size, void* d_ws, size_t ws_size,
                              hipStream_t stream) {
    const float* x    = (const float*)d_in[0];
    const float* norm = (const float*)d_in[1];
    const float* W    = (const float*)d_in[2];
    const float* V    = (const float*)d_in[3];
    const int*   src  = (const int*)d_in[4];
    const int*   dst  = (const int*)d_in[5];
    float* out = (float*)d_out;

    // workspace layout (ws): hb (bf16), offs, eidx, small bucket arrays
    unsigned short* hb = (unsigned short*)d_ws;              // N*RANK bf16 (12.8 MB)
    int*   offs        = (int*)(hb + (long)N_NODES * RANK);  // N+1
    int*   eidx        = offs + N_NODES + 1;                 // E
    int*   bhist       = eidx + N_EDGES;                     // NBUCK
    int*   bucket_offs = bhist + NBUCK;                      // NBUCK+1
    int*   bucket_cur  = bucket_offs + NBUCK + 1;            // NBUCK

    // scratch inside d_out (dead until agg_gemm writes out):
    unsigned* pairs    = (unsigned*)d_out;                   // E uint32 (6.4 MB)
    int*     blockhist = (int*)d_out + 2097152;              // at +8 MB: C_BLOCKS*NBUCK ints (1.6 MB)

    hipMemsetAsync(bhist, 0, NBUCK * sizeof(int), stream);
    gemm1_hist_kernel<<<GEMM1_BLOCKS + C_BLOCKS, 256, 0, stream>>>(x, W, hb, dst, bhist, blockhist);
    bucket_scan_kernel<<<1, 512, 0, stream>>>(bhist, bucket_offs, bucket_cur, offs);
    binscatter_kernel<<<CHUNKS * 8, 256, 0, stream>>>(src, dst, blockhist, bucket_cur, pairs);
    bucket_build_kernel<<<NBUCK, 256, 0, stream>>>(pairs, bucket_offs, offs, eidx);
    agg_gemm_kernel<<<AGG_BLOCKS, 1024, 0, stream>>>(hb, norm, V, offs, eidx, out);
}

// Round 10
// 270.827 us; speedup vs baseline: 1.3940x; 1.3940x over previous
//
#include <hip/hip_runtime.h>
#include <hip/hip_bf16.h>

#define N_NODES 100000
#define N_EDGES 1600000
#define IN_FEA 128
#define HIDDEN 128
#define RANK 64

#define NBUCK 391          // ceil(N_NODES/256): bucket b = nodes [b*256, b*256+256)
#define C_BLOCKS 1024      // hist blocks
#define EPB 1563           // edges per hist block
#define S_BLOCKS 128       // binscatter blocks (chunk = 8 hist rows)
#define CHUNK_W (EPB * 8)  // 12504 edges per scatter chunk
#define GEMM1_BLOCKS 1563  // ceil(N_NODES / 64)

// ---------------- helpers ----------------

__device__ __forceinline__ void fma4(float4& a, float s, const float4& b) {
    a.x = fmaf(s, b.x, a.x);
    a.y = fmaf(s, b.y, a.y);
    a.z = fmaf(s, b.z, a.z);
    a.w = fmaf(s, b.w, a.w);
}

__device__ __forceinline__ unsigned short f2bf_rne(float f) {
    unsigned u = __float_as_uint(f);
    u += 0x7fffu + ((u >> 16) & 1u);
    return (unsigned short)(u >> 16);
}

__device__ __forceinline__ float bf2f(unsigned short s) {
    return __uint_as_float(((unsigned)s) << 16);
}

// ---------------- fused GEMM1 + bucket histogram ----------------
// blocks [0, GEMM1_BLOCKS): h_bf = bf16(x @ W), 64 nodes/block.
// blocks [GEMM1_BLOCKS, +C_BLOCKS): per-block bucket histogram (EPB edges each).

__global__ __launch_bounds__(256) void gemm1_hist_kernel(const float* __restrict__ x,
                                                         const float* __restrict__ W,
                                                         unsigned short* __restrict__ hb,
                                                         const int* __restrict__ dst,
                                                         int* __restrict__ bhist,
                                                         int* __restrict__ blockhist) {
    __shared__ float Wl[IN_FEA * RANK];  // 32 KB (hist aliases first 1.6 KB)
    int t = threadIdx.x;

    if (blockIdx.x >= GEMM1_BLOCKS) {
        int* hist = (int*)Wl;
        int b = blockIdx.x - GEMM1_BLOCKS;
        for (int i = t; i < NBUCK; i += 256) hist[i] = 0;
        __syncthreads();
        int b0 = b * EPB;
        int b1 = min(b0 + EPB, N_EDGES);
        for (int e = b0 + t; e < b1; e += 256)
            atomicAdd(&hist[dst[e] >> 8], 1);
        __syncthreads();
        for (int i = t; i < NBUCK; i += 256) {
            int c = hist[i];
            blockhist[b * NBUCK + i] = c;
            if (c) atomicAdd(&bhist[i], c);
        }
        return;
    }

    for (int i = t; i < IN_FEA * RANK; i += 256) Wl[i] = W[i];
    __syncthreads();

    int r0 = (t & 15) * 4;
    int n0 = blockIdx.x * 64 + (t >> 4) * 4;
    const float4* x0 = (const float4*)(x + (long)min(n0 + 0, N_NODES - 1) * IN_FEA);
    const float4* x1 = (const float4*)(x + (long)min(n0 + 1, N_NODES - 1) * IN_FEA);
    const float4* x2 = (const float4*)(x + (long)min(n0 + 2, N_NODES - 1) * IN_FEA);
    const float4* x3 = (const float4*)(x + (long)min(n0 + 3, N_NODES - 1) * IN_FEA);
    float4 a0 = {0.f, 0.f, 0.f, 0.f}, a1 = a0, a2 = a0, a3 = a0;
    for (int k4 = 0; k4 < IN_FEA / 4; ++k4) {
        float4 v0 = x0[k4], v1 = x1[k4], v2 = x2[k4], v3 = x3[k4];
        int kb = k4 * 4;
        float4 w0 = *(const float4*)&Wl[(kb + 0) * RANK + r0];
        float4 w1 = *(const float4*)&Wl[(kb + 1) * RANK + r0];
        float4 w2 = *(const float4*)&Wl[(kb + 2) * RANK + r0];
        float4 w3 = *(const float4*)&Wl[(kb + 3) * RANK + r0];
        fma4(a0, v0.x, w0); fma4(a0, v0.y, w1); fma4(a0, v0.z, w2); fma4(a0, v0.w, w3);
        fma4(a1, v1.x, w0); fma4(a1, v1.y, w1); fma4(a1, v1.z, w2); fma4(a1, v1.w, w3);
        fma4(a2, v2.x, w0); fma4(a2, v2.y, w1); fma4(a2, v2.z, w2); fma4(a2, v2.w, w3);
        fma4(a3, v3.x, w0); fma4(a3, v3.y, w1); fma4(a3, v3.z, w2); fma4(a3, v3.w, w3);
    }
    float4 accs[4] = {a0, a1, a2, a3};
#pragma unroll
    for (int i = 0; i < 4; ++i) {
        if (n0 + i < N_NODES) {
            ushort4 o;
            o.x = f2bf_rne(accs[i].x); o.y = f2bf_rne(accs[i].y);
            o.z = f2bf_rne(accs[i].z); o.w = f2bf_rne(accs[i].w);
            *(ushort4*)(hb + (n0 + i) * RANK + r0) = o;
        }
    }
}

// ---------------- CSR build (rest) ----------------

__global__ void bucket_scan_kernel(const int* __restrict__ bhist,
                                   int* __restrict__ bucket_offs,
                                   int* __restrict__ bucket_cursor,
                                   int* __restrict__ offs) {
    __shared__ int sd[512];
    int t = threadIdx.x;
    int v = (t < NBUCK) ? bhist[t] : 0;
    sd[t] = v;
    __syncthreads();
    for (int off = 1; off < 512; off <<= 1) {
        int a = 0;
        if (t >= off) a = sd[t - off];
        __syncthreads();
        sd[t] += a;
        __syncthreads();
    }
    if (t < NBUCK) {
        int excl = sd[t] - v;
        bucket_offs[t] = excl;
        bucket_cursor[t] = excl;
    }
    if (t == 0) {
        bucket_offs[NBUCK] = N_EDGES;
        offs[N_NODES] = N_EDGES;
    }
}

// Fat-chunk scatter: 128 blocks x 1024 threads, one read pass. Per (block,bucket)
// run length ~= 12504/391 ~= 32 edges = 128 B -> mostly full-line writebacks
// (kills the partial-line write amplification + RFO fetches of the 1024-block form).
__global__ __launch_bounds__(1024) void binscatter_kernel(const int* __restrict__ src,
                                                          const int* __restrict__ dst,
                                                          const int* __restrict__ blockhist,
                                                          int* __restrict__ bucket_cursor,
                                                          unsigned* __restrict__ pairs) {
    __shared__ int wbase[NBUCK];
    __shared__ int cur[NBUCK];
    int t = threadIdx.x;
    int b = blockIdx.x;
    if (t < NBUCK) {
        int s = 0;
#pragma unroll
        for (int k = 0; k < 8; ++k)
            s += blockhist[(8 * b + k) * NBUCK + t];
        wbase[t] = s ? atomicAdd(&bucket_cursor[t], s) : 0;
        cur[t] = 0;
    }
    __syncthreads();
    int e0 = b * CHUNK_W;
    int e1 = min(e0 + CHUNK_W, N_EDGES);
    for (int e = e0 + t; e < e1; e += 1024) {
        int d = dst[e];
        int s = src[e];
        int bk = d >> 8;
        int lp = atomicAdd(&cur[bk], 1);
        pairs[wbase[bk] + lp] = ((unsigned)s << 8) | (unsigned)(d & 255);
    }
}

__global__ __launch_bounds__(256) void bucket_build_kernel(const unsigned* __restrict__ pairs,
                                                           const int* __restrict__ bucket_offs,
                                                           int* __restrict__ offs,
                                                           int* __restrict__ eidx) {
    __shared__ int dcnt[256];
    __shared__ int sd[256];
    __shared__ int cur[256];
    int b = blockIdx.x, t = threadIdx.x;
    int base = bucket_offs[b], end = bucket_offs[b + 1];
    dcnt[t] = 0;
    __syncthreads();
    for (int i = base + t; i < end; i += 256)
        atomicAdd(&dcnt[pairs[i] & 255u], 1);
    __syncthreads();
    int v = dcnt[t];
    sd[t] = v;
    __syncthreads();
    for (int off = 1; off < 256; off <<= 1) {
        int a = 0;
        if (t >= off) a = sd[t - off];
        __syncthreads();
        sd[t] += a;
        __syncthreads();
    }
    int excl = sd[t] - v;
    int node = b * 256 + t;
    if (node < N_NODES) offs[node] = base + excl;
    cur[t] = excl;
    __syncthreads();
    for (int i = base + t; i < end; i += 256) {
        unsigned r = pairs[i];
        int lp = atomicAdd(&cur[r & 255u], 1);
        eidx[base + lp] = (int)(r >> 8);
    }
}

// ---------------- fused aggregation + GEMM2 (R8 shape: best measured) ----------------
// 6250 blocks x 1024 threads = 16 waves, ONE NODE PER WAVE. Short-lived blocks
// retire in dispatch order -> resident waves span a contiguous node window ->
// src-row repeat gathers stay L2-warm (measured 60% hit). Do NOT make persistent.

__global__ __launch_bounds__(1024) void agg_gemm_kernel(const unsigned short* __restrict__ hb,
                                                        const float* __restrict__ norm,
                                                        const float* __restrict__ V,
                                                        const int* __restrict__ offs,
                                                        const int* __restrict__ eidx,
                                                        float* __restrict__ out) {
    __shared__ float VL[HIDDEN * 68];   // 34,816 B
    __shared__ float pls[16][64];       // 4 KB
    int t = threadIdx.x;
    {
        const float4* V4 = (const float4*)V;
#pragma unroll
        for (int k = 0; k < 2; ++k) {
            int i4 = t + 1024 * k;
            float4 v = V4[i4];
            int el = i4 << 2;
            *(float4*)&VL[(el >> 6) * 68 + (el & 63)] = v;
        }
    }
    __syncthreads();

    int wave = t >> 6, lane = t & 63;
    int node = blockIdx.x * 16 + wave;
    int beg = offs[node], end = offs[node + 1];
    float p = 1.0f;
    for (int c = beg; c < end; c += 64) {
        int n = min(64, end - c);
        int sidx = (c + lane < end) ? eidx[c + lane] : 0;
        int j = 0;
        for (; j + 8 <= n; j += 8) {
            int s0 = __shfl(sidx, j + 0);
            int s1 = __shfl(sidx, j + 1);
            int s2 = __shfl(sidx, j + 2);
            int s3 = __shfl(sidx, j + 3);
            int s4 = __shfl(sidx, j + 4);
            int s5 = __shfl(sidx, j + 5);
            int s6 = __shfl(sidx, j + 6);
            int s7 = __shfl(sidx, j + 7);
            float a0 = bf2f(hb[s0 * RANK + lane]);
            float a1 = bf2f(hb[s1 * RANK + lane]);
            float a2 = bf2f(hb[s2 * RANK + lane]);
            float a3 = bf2f(hb[s3 * RANK + lane]);
            float a4 = bf2f(hb[s4 * RANK + lane]);
            float a5 = bf2f(hb[s5 * RANK + lane]);
            float a6 = bf2f(hb[s6 * RANK + lane]);
            float a7 = bf2f(hb[s7 * RANK + lane]);
            p *= ((a0 * a1) * (a2 * a3)) * ((a4 * a5) * (a6 * a7));
        }
        for (; j + 4 <= n; j += 4) {
            int s0 = __shfl(sidx, j + 0);
            int s1 = __shfl(sidx, j + 1);
            int s2 = __shfl(sidx, j + 2);
            int s3 = __shfl(sidx, j + 3);
            float a0 = bf2f(hb[s0 * RANK + lane]);
            float a1 = bf2f(hb[s1 * RANK + lane]);
            float a2 = bf2f(hb[s2 * RANK + lane]);
            float a3 = bf2f(hb[s3 * RANK + lane]);
            p *= (a0 * a1) * (a2 * a3);
        }
        for (; j < n; ++j) {
            int s = __shfl(sidx, j);
            p *= bf2f(hb[s * RANK + lane]);
        }
    }
    pls[wave][lane] = p * norm[node];
    // wave-private slab: no barrier needed

    const float4* pw = (const float4*)pls[wave];
    const float4* rA = (const float4*)&VL[lane * 68];
    const float4* rB = (const float4*)&VL[(lane + 64) * 68];
    float accA = 0.f, accB = 0.f;
#pragma unroll
    for (int q = 0; q < 16; ++q) {
        float4 pp = pw[q];                  // broadcast read
        float4 va = rA[q];
        float4 vb = rB[q];
        accA = fmaf(pp.x, va.x, fmaf(pp.y, va.y, fmaf(pp.z, va.z, fmaf(pp.w, va.w, accA))));
        accB = fmaf(pp.x, vb.x, fmaf(pp.y, vb.y, fmaf(pp.z, vb.z, fmaf(pp.w, vb.w, accB))));
    }
    out[node * HIDDEN + lane]      = accA;
    out[node * HIDDEN + 64 + lane] = accB;
}

// ---------------- launch ----------------

extern "C" void kernel_launch(void* const* d_in, const int* in_sizes, int n_in,
                              void* d_out, int out_size, void* d_ws, size_t ws_size,
                              hipStream_t stream) {
    const float* x    = (const float*)d_in[0];
    const float* norm = (const float*)d_in[1];
    const float* W    = (const float*)d_in[2];
    const float* V    = (const float*)d_in[3];
    const int*   src  = (const int*)d_in[4];
    const int*   dst  = (const int*)d_in[5];
    float* out = (float*)d_out;

    // workspace layout (ws): hb (bf16), offs, eidx, small bucket arrays
    unsigned short* hb = (unsigned short*)d_ws;              // N*RANK bf16 (12.8 MB)
    int*   offs        = (int*)(hb + (long)N_NODES * RANK);  // N+1
    int*   eidx        = offs + N_NODES + 1;                 // E
    int*   bhist       = eidx + N_EDGES;                     // NBUCK
    int*   bucket_offs = bhist + NBUCK;                      // NBUCK+1
    int*   bucket_cur  = bucket_offs + NBUCK + 1;            // NBUCK

    // scratch inside d_out (dead until agg_gemm writes out):
    unsigned* pairs    = (unsigned*)d_out;                   // E uint32 (6.4 MB)
    int*     blockhist = (int*)d_out + 2097152;              // at +8 MB: C_BLOCKS*NBUCK ints (1.6 MB)

    hipMemsetAsync(bhist, 0, NBUCK * sizeof(int), stream);
    gemm1_hist_kernel<<<GEMM1_BLOCKS + C_BLOCKS, 256, 0, stream>>>(x, W, hb, dst, bhist, blockhist);
    bucket_scan_kernel<<<1, 512, 0, stream>>>(bhist, bucket_offs, bucket_cur, offs);
    binscatter_kernel<<<S_BLOCKS, 1024, 0, stream>>>(src, dst, blockhist, bucket_cur, pairs);
    bucket_build_kernel<<<NBUCK, 256, 0, stream>>>(pairs, bucket_offs, offs, eidx);
    agg_gemm_kernel<<<N_NODES / 16, 1024, 0, stream>>>(hb, norm, V, offs, eidx, out);
}